// Round 1
// baseline (151.396 us; speedup 1.0000x reference)
//
#include <hip/hip_runtime.h>

// GroupDense: y[row, g*64+v] = relu( sum_u x[row, g*64+u] * K[g, u, v] )
// x: [16384, 4096] fp32, K: [64, 64, 64] fp32, out: [16384, 4096] fp32.
//
// Block = 256 threads, handles one (row-tile of 64 rows) x (one group g).
// K[g] (16 KiB) staged in LDS linear [u][v]; x tile staged as [64][65] fp32
// (+1 pad -> conflict-free scalar reads). Each thread computes a 4x4
// micro-tile (4 rows x 4 output cols): 16 FMAs per 5 LDS reads.

constexpr int C_DIM = 4096;
constexpr int UNITS = 64;
constexpr int NGROUP = 64;
constexpr int ROWS_PER_BLOCK = 64;

__global__ __launch_bounds__(256, 4) void group_dense_kernel(
    const float* __restrict__ x,
    const float* __restrict__ k,
    float* __restrict__ out)
{
    __shared__ float Ks[UNITS * UNITS];      // 16 KiB, [u][v] linear
    __shared__ float Xs[ROWS_PER_BLOCK * 65]; // 16.25 KiB, [r][u] padded

    const int bid = blockIdx.x;
    const int g = bid & (NGROUP - 1);
    const int row0 = (bid >> 6) * ROWS_PER_BLOCK;
    const int tid = threadIdx.x;

    // ---- stage K[g] into LDS (coalesced float4) ----
    {
        const float4* ksrc = reinterpret_cast<const float4*>(k + (size_t)g * UNITS * UNITS);
        float4* kdst = reinterpret_cast<float4*>(Ks);
        #pragma unroll
        for (int i = 0; i < 4; ++i) {
            kdst[i * 256 + tid] = ksrc[i * 256 + tid];
        }
    }

    // ---- stage x tile [64 rows][64 u] into LDS, stride 65 ----
    {
        const int u4 = tid & 15;        // which float4 within the row
        const int rl = tid >> 4;        // 0..15
        #pragma unroll
        for (int it = 0; it < 4; ++it) {
            const int r = it * 16 + rl;
            const float4 v = *reinterpret_cast<const float4*>(
                x + (size_t)(row0 + r) * C_DIM + g * UNITS + u4 * 4);
            float* d = &Xs[r * 65 + u4 * 4];
            // stride-65 rows are not 16B aligned -> scalar writes.
            // banks (65r + 4*u4)%32 = (r + 4*u4)%32: 2-way max (free).
            d[0] = v.x; d[1] = v.y; d[2] = v.z; d[3] = v.w;
        }
    }
    __syncthreads();

    // ---- compute: thread = (vg, rq); 4 rows x 4 cols micro-tile ----
    const int vg = tid & 15;   // output col group: v0 = vg*4
    const int rq = tid >> 4;   // row quad: rows rq*4 .. rq*4+3
    const int r0 = rq * 4;

    float acc[4][4] = {};

    #pragma unroll 4
    for (int u = 0; u < UNITS; ++u) {
        const float4 kv = *reinterpret_cast<const float4*>(&Ks[u * UNITS + vg * 4]);
        float xv[4];
        #pragma unroll
        for (int i = 0; i < 4; ++i) xv[i] = Xs[(r0 + i) * 65 + u];
        #pragma unroll
        for (int i = 0; i < 4; ++i) {
            acc[i][0] = fmaf(xv[i], kv.x, acc[i][0]);
            acc[i][1] = fmaf(xv[i], kv.y, acc[i][1]);
            acc[i][2] = fmaf(xv[i], kv.z, acc[i][2]);
            acc[i][3] = fmaf(xv[i], kv.w, acc[i][3]);
        }
    }

    // ---- ReLU + coalesced float4 store ----
    #pragma unroll
    for (int i = 0; i < 4; ++i) {
        float4 o;
        o.x = fmaxf(acc[i][0], 0.0f);
        o.y = fmaxf(acc[i][1], 0.0f);
        o.z = fmaxf(acc[i][2], 0.0f);
        o.w = fmaxf(acc[i][3], 0.0f);
        *reinterpret_cast<float4*>(
            out + (size_t)(row0 + r0 + i) * C_DIM + g * UNITS + vg * 4) = o;
    }
}

extern "C" void kernel_launch(void* const* d_in, const int* in_sizes, int n_in,
                              void* d_out, int out_size, void* d_ws, size_t ws_size,
                              hipStream_t stream) {
    const float* x = (const float*)d_in[0];       // [8*2048, 4096]
    const float* k = (const float*)d_in[1];       // [64, 64, 64]
    float* out = (float*)d_out;                   // [8*2048, 4096]

    const int rows_total = in_sizes[0] / C_DIM;   // 16384
    const int grid = (rows_total / ROWS_PER_BLOCK) * NGROUP; // 256 * 64 = 16384

    group_dense_kernel<<<grid, 256, 0, stream>>>(x, k, out);
}

// Round 2
// 144.788 us; speedup vs baseline: 1.0456x; 1.0456x over previous
//
#include <hip/hip_runtime.h>

// GroupDense: y[row, g*64+v] = relu( sum_u x[row, g*64+u] * K[g, u, v] )
// x: [16384, 4096] fp32, K: [64, 64, 64] fp32, out: [16384, 4096] fp32.
//
// Block = 256 threads = 4 waves, handles 128 rows x 1 group.
//   Xs: [128 rows][64 floats] linear rows, 16B-chunk XOR swizzle within row
//       (slot' = slot ^ (row & 15)) -> conflict-free ds_read_b128.
//   Ks: [64 u][64 v] linear (kv reads naturally spread over all banks).
// Staged with global_load_lds (16B/lane, 1 KiB/wave/call); the x source
// address is pre-swizzled per-lane so the linear LDS write lands the
// swizzled layout (both-sides-or-neither rule).
// Compute: thread = (vg, rw); micro-tile 8 rows x 4 cols; per 4-u chunk:
// 8+4 ds_read_b128 for 128 FMAs (1.5 B LDS traffic per FMA, all b128).

constexpr int C_DIM = 4096;
constexpr int NGROUP = 64;
constexpr int ROWS_PER_BLOCK = 128;
constexpr int THREADS = 256;

typedef __attribute__((address_space(3))) void lds_void_t;
typedef const __attribute__((address_space(1))) void gbl_void_t;

__global__ __launch_bounds__(THREADS, 3) void group_dense_kernel(
    const float* __restrict__ x,
    const float* __restrict__ k,
    float* __restrict__ out)
{
    __shared__ float Xs[ROWS_PER_BLOCK * 64]; // 32 KiB
    __shared__ float Ks[64 * 64];             // 16 KiB

    const int bid = blockIdx.x;
    const int g = bid & (NGROUP - 1);
    const int row0 = (bid >> 6) * ROWS_PER_BLOCK;
    const int tid = threadIdx.x;
    const int lane = tid & 63;
    const int wave = tid >> 6;      // 0..3

    // ---- stage x: wave w owns rows [w*32, w*32+32), 8 calls x 4 rows ----
    {
        const int l4 = lane >> 4;    // row within 4-row call
        const int ch = lane & 15;    // 16B chunk slot within row
        #pragma unroll
        for (int c = 0; c < 8; ++c) {
            const int rl = wave * 32 + c * 4 + l4;          // local row
            const int chunk = ch ^ (rl & 15);               // pre-swizzled src
            const float* src = x + (size_t)(row0 + rl) * C_DIM + g * 64 + chunk * 4;
            float* dst = &Xs[(wave * 32 + c * 4) * 64];     // wave-uniform, linear
            __builtin_amdgcn_global_load_lds((gbl_void_t*)src, (lds_void_t*)dst, 16, 0, 0);
        }
        // ---- stage K[g]: 4 calls x 1 KiB per wave, fully linear ----
        #pragma unroll
        for (int c = 0; c < 4; ++c) {
            const float* src = k + (size_t)g * 4096 + (wave * 4 + c) * 256 + lane * 4;
            float* dst = &Ks[(wave * 4 + c) * 256];
            __builtin_amdgcn_global_load_lds((gbl_void_t*)src, (lds_void_t*)dst, 16, 0, 0);
        }
    }
    __syncthreads();

    // ---- compute: thread = (vg, rw); rows rw+16j (j=0..7), cols vg*4..+3 ----
    const int vg = tid & 15;
    const int rw = tid >> 4;        // 0..15

    float acc[8][4] = {};

    // per-row swizzled base (float index): r*64 + (r&15)*4; chunk walk via XOR
    int xbase[8];
    #pragma unroll
    for (int j = 0; j < 8; ++j) {
        const int r = rw + 16 * j;
        xbase[j] = r * 64 + (r & 15) * 4;
    }

    #pragma unroll
    for (int s0 = 0; s0 < 16; ++s0) {       // u chunk = [4*s0, 4*s0+4)
        float kv[4][4];
        #pragma unroll
        for (int i = 0; i < 4; ++i) {
            const float4 t = *reinterpret_cast<const float4*>(
                &Ks[(s0 * 4 + i) * 64 + vg * 4]);
            kv[i][0] = t.x; kv[i][1] = t.y; kv[i][2] = t.z; kv[i][3] = t.w;
        }
        float xv[8][4];
        #pragma unroll
        for (int j = 0; j < 8; ++j) {
            const float4 t = *reinterpret_cast<const float4*>(
                &Xs[xbase[j] ^ (s0 * 4)]);
            xv[j][0] = t.x; xv[j][1] = t.y; xv[j][2] = t.z; xv[j][3] = t.w;
        }
        #pragma unroll
        for (int j = 0; j < 8; ++j)
            #pragma unroll
            for (int i = 0; i < 4; ++i)
                #pragma unroll
                for (int c = 0; c < 4; ++c)
                    acc[j][c] = fmaf(xv[j][i], kv[i][c], acc[j][c]);
    }

    // ---- ReLU + coalesced float4 stores (16 lanes x 16B = 256B per row) ----
    const size_t obase = (size_t)row0 * C_DIM + g * 64 + vg * 4;
    #pragma unroll
    for (int j = 0; j < 8; ++j) {
        const int r = rw + 16 * j;
        float4 o;
        o.x = fmaxf(acc[j][0], 0.0f);
        o.y = fmaxf(acc[j][1], 0.0f);
        o.z = fmaxf(acc[j][2], 0.0f);
        o.w = fmaxf(acc[j][3], 0.0f);
        *reinterpret_cast<float4*>(out + obase + (size_t)r * C_DIM) = o;
    }
}

extern "C" void kernel_launch(void* const* d_in, const int* in_sizes, int n_in,
                              void* d_out, int out_size, void* d_ws, size_t ws_size,
                              hipStream_t stream) {
    const float* x = (const float*)d_in[0];   // [16384, 4096]
    const float* k = (const float*)d_in[1];   // [64, 64, 64]
    float* out = (float*)d_out;

    const int rows_total = in_sizes[0] / C_DIM;                   // 16384
    const int grid = (rows_total / ROWS_PER_BLOCK) * NGROUP;      // 128*64 = 8192

    group_dense_kernel<<<grid, THREADS, 0, stream>>>(x, k, out);
}